// Round 1
// baseline (613.835 us; speedup 1.0000x reference)
//
#include <hip/hip_runtime.h>

// Problem constants (match reference)
#define B_    32
#define C_    128
#define T_    64
#define E_    512
#define NPOS_ 256

// One block per (b,c) pair. 256 threads.
// Phase 1: argmin over NPOS candidates (1 candidate/thread).
// Phase 2: stage spatial_table[best] row (512 f32 = 2 KiB) in LDS.
// Phase 3: write T_ rows of (spe + temporal[t]) with coalesced float4 stores.
__global__ __launch_bounds__(256) void pe_fused_kernel(
    const float* __restrict__ pos,        // (B, C, 3)
    const float* __restrict__ positions,  // (NPOS, 3)
    const float* __restrict__ spat,       // (NPOS, E)
    const float* __restrict__ temp,       // (T, E)
    float* __restrict__ out)              // (B, C*T, E)
{
    const int bc  = blockIdx.x;     // b*C_ + c
    const int tid = threadIdx.x;    // 0..255

    // ---- Phase 1: per-thread distance (reference formula: pp - 2*dot + qq) ----
    const float px = pos[bc * 3 + 0];
    const float py = pos[bc * 3 + 1];
    const float pz = pos[bc * 3 + 2];
    const float pp = px * px + py * py + pz * pz;

    const float qx = positions[tid * 3 + 0];
    const float qy = positions[tid * 3 + 1];
    const float qz = positions[tid * 3 + 2];
    const float dot = px * qx + py * qy + pz * qz;
    const float qq  = qx * qx + qy * qy + qz * qz;

    float d2  = pp - 2.0f * dot + qq;
    int   idx = tid;

    // wave (64-lane) argmin reduce, lowest-index tie-break
    #pragma unroll
    for (int off = 32; off > 0; off >>= 1) {
        float od = __shfl_down(d2, off);
        int   oi = __shfl_down(idx, off);
        if (od < d2 || (od == d2 && oi < idx)) { d2 = od; idx = oi; }
    }

    __shared__ float sd[4];
    __shared__ int   si[4];
    __shared__ int   best_idx;
    const int wave = tid >> 6;
    if ((tid & 63) == 0) { sd[wave] = d2; si[wave] = idx; }
    __syncthreads();
    if (tid == 0) {
        float bd = sd[0]; int bi = si[0];
        #pragma unroll
        for (int w = 1; w < 4; ++w) {
            if (sd[w] < bd || (sd[w] == bd && si[w] < bi)) { bd = sd[w]; bi = si[w]; }
        }
        best_idx = bi;
    }
    __syncthreads();
    const int bi = best_idx;

    // ---- Phase 2: stage spe row in LDS (512 floats; 2 per thread via float2) ----
    __shared__ float spe[E_];
    ((float2*)spe)[tid] = ((const float2*)(spat + (size_t)bi * E_))[tid];
    __syncthreads();

    // ---- Phase 3: stream output. 256 threads * float4 = 4 KiB = 2 rows/iter ----
    float* obase = out + (size_t)bc * (T_ * E_);
    const int e4    = (tid & 127) * 4;  // float4 column within a row
    const int thalf = tid >> 7;         // which of the 2 rows this iter
    const float4 s = *(const float4*)(spe + e4);

    #pragma unroll 4
    for (int i = 0; i < T_ / 2; ++i) {
        const int t = 2 * i + thalf;
        const float4 tv = *(const float4*)(temp + (size_t)t * E_ + e4);
        float4 o;
        o.x = s.x + tv.x;
        o.y = s.y + tv.y;
        o.z = s.z + tv.z;
        o.w = s.w + tv.w;
        *(float4*)(obase + (size_t)t * E_ + e4) = o;
    }
}

extern "C" void kernel_launch(void* const* d_in, const int* in_sizes, int n_in,
                              void* d_out, int out_size, void* d_ws, size_t ws_size,
                              hipStream_t stream) {
    const float* pos       = (const float*)d_in[0];  // (B, C, 3)
    const float* positions = (const float*)d_in[1];  // (NPOS, 3)
    const float* spat      = (const float*)d_in[2];  // (NPOS, E)
    const float* temp      = (const float*)d_in[3];  // (T, E)
    float* out             = (float*)d_out;          // (B, C*T, E)

    dim3 grid(B_ * C_);
    dim3 block(256);
    pe_fused_kernel<<<grid, block, 0, stream>>>(pos, positions, spat, temp, out);
}